// Round 9
// baseline (98.921 us; speedup 1.0000x reference)
//
#include <hip/hip_runtime.h>

#define IMG 8
#define LH 150
#define LQ 10
#define KITER 10   // 9 scan steps + final conv
#define ROW (IMG * IMG + 2)   // 66 floats per batch row

// DPP controls: shifts within each 16-lane DPP row. bound_ctrl=true => lanes
// with no in-row source read 0.
#define DPP_SHR1 0x111   // lane i <- lane i-1
#define DPP_SHL1 0x101   // lane i <- lane i+1
#define DPP_SHR8 0x118   // lane i <- lane i-8  (h=1 half reads h=0 half)
#define DPP_SHL8 0x108   // lane i <- lane i+8  (h=0 half reads h=1 half)
template <int CTRL>
__device__ __forceinline__ float dppf(float v) {
    return __builtin_bit_cast(float,
        __builtin_amdgcn_update_dpp(0, __builtin_bit_cast(int, v),
                                    CTRL, 0xF, 0xF, true));
}

// ds_bpermute (byte address); epilogue only. Full-wave convergence required.
__device__ __forceinline__ float bperm(int byte_addr, float v) {
    return __builtin_bit_cast(float,
        __builtin_amdgcn_ds_bpermute(byte_addr, __builtin_bit_cast(int, v)));
}

// ---------------------------------------------------------------------------
// Pre-kernel: collapse h/r convs (exact — no nonlinearity between h and r).
//   ws[t] = sum_c Wr[c] * Wh[c, t]  (t=0..8),  ws[9] = sum_c Wr[c] * bh[c]
// ---------------------------------------------------------------------------
__global__ void weff_kernel(const float* __restrict__ Wh,
                            const float* __restrict__ bh,
                            const float* __restrict__ Wr,
                            float* __restrict__ ws) {
    const int wv = threadIdx.x >> 6;   // 0..9 (wave-uniform)
    const int lane = threadIdx.x & 63;
    float partial = 0.f;
    for (int c = lane; c < LH; c += 64) {
        const float wr = Wr[c];
        partial += wr * ((wv < 9) ? Wh[c * 9 + wv] : bh[c]);
    }
    #pragma unroll
    for (int off = 32; off > 0; off >>= 1)
        partial += __shfl_xor(partial, off);   // full wave active
    if (lane == 0) ws[wv] = partial;
}

// ---------------------------------------------------------------------------
// Round-9 layout: one wave = FOUR items; lane = (item i = lane>>4,
// y-half h = (lane>>3)&1, col x = lane&7); each lane holds 4 rows
// (y = h*4 .. h*4+3) in V[0..3].  All neighbor access is DPP (VALU pipe,
// zero LDS): dx=+-1 via row_shr1/shl1 + x-edge mask; the y half-boundary via
// row_shr8/shl8 whose bound_ctrl=0 zeroes the y=-1 / y=8 pads for free.
// Halving per-lane state vs round 8 (qr: 80->40 VGPRs) doubles occupancy to
// 4 waves/SIMD — the round-8 plateau theory is exposed-latency at 2 waves.
// Weights stay wave-uniform SGPR reads (per-lane arrays = AGPR trap, R7).
// ---------------------------------------------------------------------------
__global__ __launch_bounds__(256, 4) void vin_kernel(
    const float* __restrict__ S,
    const float* __restrict__ Wq,
    const float* __restrict__ w,
    const float* __restrict__ Wfc,
    const float* __restrict__ ws,
    float* __restrict__ out,
    int B) {
    const int wave = threadIdx.x >> 6;
    const int lane = threadIdx.x & 63;
    const long wid = (long)blockIdx.x * 4 + wave;   // 4 items per wave
    if (wid * 4 >= B) return;                        // wave-uniform

    const int x = lane & 7;
    const int ioff = (lane >> 4) * ROW;              // item offset (per-lane)
    const float mskL = (x == 0) ? 0.f : 1.f;
    const float mskR = (x == 7) ? 0.f : 1.f;

    const float* Sb = S + wid * 4 * ROW;
    const int ybase = ((lane >> 3) & 1) * 32 + x;    // (h*4+0)*8 + x

    // Half-column load: V[yy] = grid(h*4+yy, x) of item i.
    float X[4];
    #pragma unroll
    for (int yy = 0; yy < 4; ++yy) X[yy] = Sb[ioff + ybase + yy * 8];
    const int s1 = (int)Sb[ioff + 64];
    const int s2 = (int)Sb[ioff + 65];

    // Build the 6-row shifted set {U,0,1,2,3,D} x {C,L,R} from a 4-reg column.
    float C[6], L[6], R[6];
    auto expand = [&](const float V[4]) {
        C[0] = dppf<DPP_SHR8>(V[3]);   // row above half (0 at y=-1 pad)
        C[1] = V[0]; C[2] = V[1]; C[3] = V[2]; C[4] = V[3];
        C[5] = dppf<DPP_SHL8>(V[0]);   // row below half (0 at y=8 pad)
        #pragma unroll
        for (int j = 0; j < 6; ++j) {
            L[j] = dppf<DPP_SHR1>(C[j]) * mskL;
            R[j] = dppf<DPP_SHL1>(C[j]) * mskR;
        }
    };
    // 9-tap conv at local row yy, reference tap order t=0..8.
    auto conv9 = [&](int yy, const float* wt, float acc) {
        acc = fmaf(L[yy],     wt[0], acc);
        acc = fmaf(C[yy],     wt[1], acc);
        acc = fmaf(R[yy],     wt[2], acc);
        acc = fmaf(L[yy + 1], wt[3], acc);
        acc = fmaf(C[yy + 1], wt[4], acc);
        acc = fmaf(R[yy + 1], wt[5], acc);
        acc = fmaf(L[yy + 2], wt[6], acc);
        acc = fmaf(C[yy + 2], wt[7], acc);
        acc = fmaf(R[yy + 2], wt[8], acc);
        return acc;
    };

    // ---- r = conv(X, Weff, pad=1) + beff ----
    expand(X);
    float r[4];
    #pragma unroll
    for (int yy = 0; yy < 4; ++yy) r[yy] = conv9(yy, ws, ws[9]);

    // ---- qr[o][yy] = conv(r, Wq, pad=1) — loop-invariant base ----
    expand(r);
    float qr[LQ][4];
    #pragma unroll
    for (int o = 0; o < LQ; ++o)
        #pragma unroll
        for (int yy = 0; yy < 4; ++yy)
            qr[o][yy] = conv9(yy, Wq + o * 9, 0.f);

    // v0 = max_o qr[o]
    float v[4];
    #pragma unroll
    for (int yy = 0; yy < 4; ++yy) {
        float m = qr[0][yy];
        #pragma unroll
        for (int o = 1; o < LQ; ++o) m = fmaxf(m, qr[o][yy]);
        v[yy] = m;
    }

    // ---- 9 scan steps: DPP + fma + running max. Zero LDS ops. ----
    #pragma unroll 1   // keep body in I-cache; inner loops fully unrolled
    for (int k = 0; k < KITER - 1; ++k) {
        expand(v);
        float m[4];
        #pragma unroll
        for (int o = 0; o < LQ; ++o) {
            #pragma unroll
            for (int yy = 0; yy < 4; ++yy) {
                const float acc = conv9(yy, w + o * 9, qr[o][yy]);
                m[yy] = (o == 0) ? acc : fmaxf(m[yy], acc);
            }
        }
        #pragma unroll
        for (int yy = 0; yy < 4; ++yy) v[yy] = m[yy];
    }

    // ---- Final conv fused with pixel-select + FC ----
    float wfc[LQ];
    #pragma unroll
    for (int o = 0; o < LQ; ++o) wfc[o] = Wfc[x * LQ + o];   // lane x -> logit x

    expand(v);
    const bool sb0 = (s1 & 1) != 0, sb1 = (s1 & 2) != 0;
    // lane of (item i, half s1>=4, x=s2), in bytes
    const int selb = ((lane & 48) + (s1 >> 2) * 8 + s2) << 2;
    float logit = 0.f;
    #pragma unroll
    for (int o = 0; o < LQ; ++o) {
        float q[4];
        #pragma unroll
        for (int yy = 0; yy < 4; ++yy) q[yy] = conv9(yy, w + o * 9, qr[o][yy]);
        // local-row select (s1&3) via 2-level cndmask, then lane select via bperm
        const float t0 = sb0 ? q[1] : q[0];
        const float t1 = sb0 ? q[3] : q[2];
        const float qy = sb1 ? t1 : t0;
        logit = fmaf(bperm(selb, qy), wfc[o], logit);   // full convergence
    }

    // h==0 lanes store: 4 items x 8 logits per wave, coalesced 32B groups.
    if ((lane & 8) == 0)
        out[wid * 32 + (lane >> 4) * 8 + x] = logit;
}

extern "C" void kernel_launch(void* const* d_in, const int* in_sizes, int n_in,
                              void* d_out, int out_size, void* d_ws, size_t ws_size,
                              hipStream_t stream) {
    const float* S   = (const float*)d_in[0];
    const float* Wh  = (const float*)d_in[1];
    const float* bh  = (const float*)d_in[2];
    const float* Wr  = (const float*)d_in[3];
    const float* Wq  = (const float*)d_in[4];
    const float* w   = (const float*)d_in[5];
    const float* Wfc = (const float*)d_in[6];
    float* out = (float*)d_out;
    float* ws  = (float*)d_ws;

    const int B = in_sizes[0] / ROW;

    weff_kernel<<<1, 640, 0, stream>>>(Wh, bh, Wr, ws);

    // 4 waves/block, 4 items/wave => 16 items per block.
    const int grid = (B + 15) / 16;
    vin_kernel<<<grid, 256, 0, stream>>>(S, Wq, w, Wfc, ws, out, B);
}

// Round 10
// 98.875 us; speedup vs baseline: 1.0005x; 1.0005x over previous
//
#include <hip/hip_runtime.h>

#define IMG 8
#define LH 150
#define LQ 10
#define KITER 10   // 9 scan steps + final conv
#define ROW (IMG * IMG + 2)   // 66 floats per batch row

// DPP controls: shifts within each 16-lane DPP row. bound_ctrl=true => lanes
// with no in-row source read 0.
#define DPP_SHR1 0x111   // lane i <- lane i-1
#define DPP_SHL1 0x101   // lane i <- lane i+1
#define DPP_SHR8 0x118   // lane i <- lane i-8  (h=1 half reads h=0 half)
#define DPP_SHL8 0x108   // lane i <- lane i+8  (h=0 half reads h=1 half)
template <int CTRL>
__device__ __forceinline__ float dppf(float v) {
    return __builtin_bit_cast(float,
        __builtin_amdgcn_update_dpp(0, __builtin_bit_cast(int, v),
                                    CTRL, 0xF, 0xF, true));
}

// ds_bpermute (byte address); epilogue only. Full-wave convergence required.
__device__ __forceinline__ float bperm(int byte_addr, float v) {
    return __builtin_bit_cast(float,
        __builtin_amdgcn_ds_bpermute(byte_addr, __builtin_bit_cast(int, v)));
}

// ---------------------------------------------------------------------------
// Single fused kernel (round 10): the h/r collapse (Weff) is computed by each
// wave from Wh/bh/Wr directly (~200 one-time inst) — removes the serialized
// 1-block weff dispatch and the d_ws round-trip entirely.
//
// Layout (validated in round 9): one wave = FOUR items; lane = (item i =
// lane>>4, y-half h = (lane>>3)&1, col x = lane&7); each lane holds 4 rows in
// registers. All neighbor access is DPP (VALU pipe, zero LDS in the k-loop):
// dx=+-1 via row_shr1/shl1 + x-edge mask; y half-boundary via row_shr8/shl8
// whose bound_ctrl=0 zeroes the y=-1 / y=8 pads for free.
// Weights stay wave-uniform SGPR reads (per-lane arrays = AGPR trap, R7).
// k-loop: #pragma unroll 3 (9=3x3) to CSE the 90 weight s_loads across
// iterations; channel-paired v_max3 trees (fmax is exact => bitwise same).
// ---------------------------------------------------------------------------
__global__ __launch_bounds__(256, 4) void vin_kernel(
    const float* __restrict__ S,
    const float* __restrict__ Wh,
    const float* __restrict__ bh,
    const float* __restrict__ Wr,
    const float* __restrict__ Wq,
    const float* __restrict__ w,
    const float* __restrict__ Wfc,
    float* __restrict__ out,
    int B) {
    const int wave = threadIdx.x >> 6;
    const int lane = threadIdx.x & 63;
    const long wid = (long)blockIdx.x * 4 + wave;   // 4 items per wave
    if (wid * 4 >= B) return;                        // wave-uniform

    const int x = lane & 7;
    const int ioff = (lane >> 4) * ROW;              // item offset (per-lane)
    const float mskL = (x == 0) ? 0.f : 1.f;
    const float mskR = (x == 7) ? 0.f : 1.f;

    // ---- Fused Weff: part[t] = sum_c Wr[c]*Wh[c,t], part[9] = sum Wr[c]*bh[c]
    float part[10];
    #pragma unroll
    for (int t = 0; t < 10; ++t) part[t] = 0.f;
    for (int c = lane; c < LH; c += 64) {            // divergent trip count ok:
        const float wr = Wr[c];                      // no cross-lane ops inside
        #pragma unroll
        for (int t = 0; t < 9; ++t) part[t] = fmaf(wr, Wh[c * 9 + t], part[t]);
        part[9] = fmaf(wr, bh[c], part[9]);
    }
    #pragma unroll
    for (int off = 32; off > 0; off >>= 1) {         // full-wave butterfly
        #pragma unroll
        for (int t = 0; t < 10; ++t) part[t] += __shfl_xor(part[t], off);
    }
    // part[0..8] = Weff taps, part[9] = beff (uniform values in VGPRs)

    const float* Sb = S + wid * 4 * ROW;
    const int ybase = ((lane >> 3) & 1) * 32 + x;    // (h*4+0)*8 + x

    // Half-column load: X[yy] = grid(h*4+yy, x) of item i.
    float X[4];
    #pragma unroll
    for (int yy = 0; yy < 4; ++yy) X[yy] = Sb[ioff + ybase + yy * 8];
    const int s1 = (int)Sb[ioff + 64];
    const int s2 = (int)Sb[ioff + 65];

    // Shifted row set {U,0,1,2,3,D} x {C,L,R} from a 4-reg half-column.
    float C[6], L[6], R[6];
    auto expand = [&](const float V[4]) {
        C[0] = dppf<DPP_SHR8>(V[3]);   // row above half (0 at y=-1 pad)
        C[1] = V[0]; C[2] = V[1]; C[3] = V[2]; C[4] = V[3];
        C[5] = dppf<DPP_SHL8>(V[0]);   // row below half (0 at y=8 pad)
        #pragma unroll
        for (int j = 0; j < 6; ++j) {
            L[j] = dppf<DPP_SHR1>(C[j]) * mskL;
            R[j] = dppf<DPP_SHL1>(C[j]) * mskR;
        }
    };
    // 9-tap conv at local row yy, reference tap order t=0..8.
    auto conv9 = [&](int yy, const float* wt, float acc) {
        acc = fmaf(L[yy],     wt[0], acc);
        acc = fmaf(C[yy],     wt[1], acc);
        acc = fmaf(R[yy],     wt[2], acc);
        acc = fmaf(L[yy + 1], wt[3], acc);
        acc = fmaf(C[yy + 1], wt[4], acc);
        acc = fmaf(R[yy + 1], wt[5], acc);
        acc = fmaf(L[yy + 2], wt[6], acc);
        acc = fmaf(C[yy + 2], wt[7], acc);
        acc = fmaf(R[yy + 2], wt[8], acc);
        return acc;
    };

    // ---- r = conv(X, Weff, pad=1) + beff ----
    expand(X);
    float r[4];
    #pragma unroll
    for (int yy = 0; yy < 4; ++yy) r[yy] = conv9(yy, part, part[9]);

    // ---- qr[o][yy] = conv(r, Wq, pad=1) — loop-invariant base ----
    expand(r);
    float qr[LQ][4];
    #pragma unroll
    for (int o = 0; o < LQ; ++o)
        #pragma unroll
        for (int yy = 0; yy < 4; ++yy)
            qr[o][yy] = conv9(yy, Wq + o * 9, 0.f);

    // v0 = max_o qr[o]  (paired -> v_max3; fmax is exact, any tree identical)
    float v[4];
    #pragma unroll
    for (int yy = 0; yy < 4; ++yy) {
        float m = fmaxf(qr[0][yy], qr[1][yy]);
        #pragma unroll
        for (int op = 1; op < 5; ++op)
            m = fmaxf(m, fmaxf(qr[2 * op][yy], qr[2 * op + 1][yy]));
        v[yy] = m;
    }

    // ---- 9 scan steps: DPP + fma + paired max3. Zero LDS ops. ----
    #pragma unroll 3   // 9 = 3x3: CSE weight s_loads across iters, no peel
    for (int k = 0; k < KITER - 1; ++k) {
        expand(v);
        float m[4];
        #pragma unroll
        for (int op = 0; op < 5; ++op) {
            float a0[4], a1[4];
            #pragma unroll
            for (int yy = 0; yy < 4; ++yy)
                a0[yy] = conv9(yy, w + (2 * op) * 9, qr[2 * op][yy]);
            #pragma unroll
            for (int yy = 0; yy < 4; ++yy)
                a1[yy] = conv9(yy, w + (2 * op + 1) * 9, qr[2 * op + 1][yy]);
            #pragma unroll
            for (int yy = 0; yy < 4; ++yy) {
                const float p = fmaxf(a0[yy], a1[yy]);
                m[yy] = (op == 0) ? p : fmaxf(m[yy], p);   // v_max3 form
            }
        }
        #pragma unroll
        for (int yy = 0; yy < 4; ++yy) v[yy] = m[yy];
    }

    // ---- Final conv fused with pixel-select + FC ----
    float wfc[LQ];
    #pragma unroll
    for (int o = 0; o < LQ; ++o) wfc[o] = Wfc[x * LQ + o];   // lane x -> logit x

    expand(v);
    const bool sb0 = (s1 & 1) != 0, sb1 = (s1 & 2) != 0;
    // lane of (item i, half s1>=4, x=s2), in bytes
    const int selb = ((lane & 48) + (s1 >> 2) * 8 + s2) << 2;
    float logit = 0.f;
    #pragma unroll
    for (int o = 0; o < LQ; ++o) {
        float q[4];
        #pragma unroll
        for (int yy = 0; yy < 4; ++yy) q[yy] = conv9(yy, w + o * 9, qr[o][yy]);
        // local-row select (s1&3) via 2-level cndmask, then lane select via bperm
        const float t0 = sb0 ? q[1] : q[0];
        const float t1 = sb0 ? q[3] : q[2];
        const float qy = sb1 ? t1 : t0;
        logit = fmaf(bperm(selb, qy), wfc[o], logit);   // full convergence
    }

    // h==0 lanes store: 4 items x 8 logits per wave, coalesced 32B groups.
    if ((lane & 8) == 0)
        out[wid * 32 + (lane >> 4) * 8 + x] = logit;
}

extern "C" void kernel_launch(void* const* d_in, const int* in_sizes, int n_in,
                              void* d_out, int out_size, void* d_ws, size_t ws_size,
                              hipStream_t stream) {
    const float* S   = (const float*)d_in[0];
    const float* Wh  = (const float*)d_in[1];
    const float* bh  = (const float*)d_in[2];
    const float* Wr  = (const float*)d_in[3];
    const float* Wq  = (const float*)d_in[4];
    const float* w   = (const float*)d_in[5];
    const float* Wfc = (const float*)d_in[6];
    float* out = (float*)d_out;

    const int B = in_sizes[0] / ROW;

    // Single fused dispatch: 4 waves/block, 4 items/wave => 16 items/block.
    const int grid = (B + 15) / 16;
    vin_kernel<<<grid, 256, 0, stream>>>(S, Wh, bh, Wr, Wq, w, Wfc, out, B);
}